// Round 1
// baseline (683.374 us; speedup 1.0000x reference)
//
#include <hip/hip_runtime.h>

// Problem constants (B=8, N=8192, C=256, K=8, nblocks=8, blk=32)
#define NPTS 8192
#define CH   256
#define KNB  8
#define NROWS 65536   // B*N

// ---------------------------------------------------------------------------
// Stage 1: per row (b,n):
//   s1 = 0.95*x[row] + 0.05 * sum_k w_k * x[b, idx_k]
//   f[k*32+q]   = sum_p w1[k,q,p] * s1[k*32+p]
//   t[s*8+l]    = bias[s*8+l] + sum_r w2[l,s,r] * f[r*8+l]
// One 256-thread block per row; thread c owns channel c.
// ---------------------------------------------------------------------------
__global__ __launch_bounds__(256) void pm_stage1(
    const float* __restrict__ x, const float* __restrict__ dist,
    const int* __restrict__ idx, const float* __restrict__ w1,
    const float* __restrict__ w2, const float* __restrict__ bias,
    float* __restrict__ t)
{
    const int row = blockIdx.x;          // b*N + n
    const int b   = row >> 13;           // row / 8192
    const int c   = threadIdx.x;         // channel 0..255

    __shared__ float s1[CH];
    __shared__ float fmid[CH];

    // Softmax weights: wave-uniform addresses -> scalar loads, redundant VALU ok
    float d[KNB];
#pragma unroll
    for (int k = 0; k < KNB; ++k) d[k] = dist[(size_t)row * KNB + k];
    float mn = d[0];
#pragma unroll
    for (int k = 1; k < KNB; ++k) mn = fminf(mn, d[k]);
    float e[KNB];
    float sum = 0.f;
#pragma unroll
    for (int k = 0; k < KNB; ++k) { e[k] = __expf(mn - d[k]); sum += e[k]; }
    const float inv = 0.05f / sum;

    int nb[KNB];
#pragma unroll
    for (int k = 0; k < KNB; ++k) nb[k] = idx[(size_t)row * KNB + k];

    // Gather-blend: each access is a coalesced 1KiB row read
    const float* xb = x + (size_t)b * NPTS * CH;
    float v = 0.95f * x[(size_t)row * CH + c];
#pragma unroll
    for (int k = 0; k < KNB; ++k)
        v += (e[k] * inv) * xb[(size_t)nb[k] * CH + c];
    s1[c] = v;
    __syncthreads();

    // Monarch stage A: thread c = (kk = c>>5, q = c&31); w1 row base = c*32
    {
        const float4* wrow = (const float4*)(w1 + c * 32);
        const float*  sb   = &s1[c & ~31];
        float acc = 0.f;
#pragma unroll
        for (int p4 = 0; p4 < 8; ++p4) {
            float4 w = wrow[p4];
            acc += w.x * sb[p4 * 4 + 0];
            acc += w.y * sb[p4 * 4 + 1];
            acc += w.z * sb[p4 * 4 + 2];
            acc += w.w * sb[p4 * 4 + 3];
        }
        fmid[c] = acc;
    }
    __syncthreads();

    // Monarch stage B: thread c = (l = c&7, s = c>>3)
    {
        const int l = c & 7;
        const int s = c >> 3;
        const float4* wrow = (const float4*)(w2 + (l * 32 + s) * 32);
        float acc = bias[c];
#pragma unroll
        for (int r4 = 0; r4 < 8; ++r4) {
            float4 w = wrow[r4];
            acc += w.x * fmid[(r4 * 4 + 0) * 8 + l];
            acc += w.y * fmid[(r4 * 4 + 1) * 8 + l];
            acc += w.z * fmid[(r4 * 4 + 2) * 8 + l];
            acc += w.w * fmid[(r4 * 4 + 3) * 8 + l];
        }
        t[(size_t)row * CH + c] = acc;
    }
}

// ---------------------------------------------------------------------------
// Stage 2: out[row] = 0.95*t[row] + 0.05*sum_k w_k*t[b, idx_k] + rf[row]
// One wave (64 lanes) per row, float4 per lane; 4 rows per 256-thread block.
// ---------------------------------------------------------------------------
__global__ __launch_bounds__(256) void pm_stage2(
    const float* __restrict__ t, const float* __restrict__ dist,
    const int* __restrict__ idx, const float* __restrict__ rf,
    float* __restrict__ out)
{
    const int row  = blockIdx.x * 4 + (threadIdx.x >> 6);
    const int lane = threadIdx.x & 63;
    const int b    = row >> 13;

    float d[KNB];
#pragma unroll
    for (int k = 0; k < KNB; ++k) d[k] = dist[(size_t)row * KNB + k];
    float mn = d[0];
#pragma unroll
    for (int k = 1; k < KNB; ++k) mn = fminf(mn, d[k]);
    float e[KNB];
    float sum = 0.f;
#pragma unroll
    for (int k = 0; k < KNB; ++k) { e[k] = __expf(mn - d[k]); sum += e[k]; }
    const float inv = 0.05f / sum;

    const float4* t4 = (const float4*)t;
    float4 acc = t4[(size_t)row * 64 + lane];
    acc.x *= 0.95f; acc.y *= 0.95f; acc.z *= 0.95f; acc.w *= 0.95f;

    const size_t bbase = (size_t)b * NPTS * 64;
#pragma unroll
    for (int k = 0; k < KNB; ++k) {
        const int nb = idx[(size_t)row * KNB + k];
        const float4 g = t4[bbase + (size_t)nb * 64 + lane];
        const float w = e[k] * inv;
        acc.x += w * g.x; acc.y += w * g.y; acc.z += w * g.z; acc.w += w * g.w;
    }

    const float4 r = ((const float4*)rf)[(size_t)row * 64 + lane];
    acc.x += r.x; acc.y += r.y; acc.z += r.z; acc.w += r.w;
    ((float4*)out)[(size_t)row * 64 + lane] = acc;
}

extern "C" void kernel_launch(void* const* d_in, const int* in_sizes, int n_in,
                              void* d_out, int out_size, void* d_ws, size_t ws_size,
                              hipStream_t stream) {
    const float* x    = (const float*)d_in[0];
    const float* dist = (const float*)d_in[1];
    const int*   idx  = (const int*)d_in[2];
    const float* rf   = (const float*)d_in[3];
    const float* w1   = (const float*)d_in[4];
    const float* w2   = (const float*)d_in[5];
    const float* bias = (const float*)d_in[6];
    float* out = (float*)d_out;
    float* t   = (float*)d_ws;   // 64 MiB intermediate (B,N,C) fp32

    pm_stage1<<<NROWS, 256, 0, stream>>>(x, dist, idx, w1, w2, bias, t);
    pm_stage2<<<NROWS / 4, 256, 0, stream>>>(t, dist, idx, rf, out);
}

// Round 2
// 307.342 us; speedup vs baseline: 2.2235x; 2.2235x over previous
//
#include <hip/hip_runtime.h>

// Problem constants (B=8, N=8192, C=256, K=8, nblocks=8, blk=32)
#define NPTS 8192
#define CH   256
#define KNB  8
#define NROWS 65536        // B*N
#define ROWS_PER_BLK 16    // rows each block processes
#define ROWS_PER_IT  4     // rows per barrier-delimited iteration (256 thr / 64 lanes)

// ---------------------------------------------------------------------------
// Stage 1, tiled: block = 256 threads, processes 16 rows in 4 iterations.
// Weights are hoisted into registers ONCE per thread (w1 row + w2 row = 64 VGPR)
// and reused for all 16 rows, eliminating the 64KiB-per-row L1 weight stream.
// Blend phase uses float4 gathers (1 KiB per wave instruction).
// ---------------------------------------------------------------------------
__global__ __launch_bounds__(256) void pm_stage1(
    const float* __restrict__ x, const float* __restrict__ dist,
    const int* __restrict__ idx, const float* __restrict__ w1,
    const float* __restrict__ w2, const float* __restrict__ bias,
    float* __restrict__ t)
{
    const int c = threadIdx.x;             // channel this thread owns in monarch phases

    __shared__ float s1[ROWS_PER_IT][CH];
    __shared__ float fmid[ROWS_PER_IT][CH];

    // ---- hoisted weights (registers, reused for all 16 rows) ----
    // stage A: c = (k = c>>5, q = c&31); w1 row = w1[c*32 .. c*32+31]
    // stage B: c = (l2 = c&7, s = c>>3); w2 row = w2[(l2*32+s)*32 .. +31]
    float4 w1r[8], w2r[8];
    {
        const float4* w1p = (const float4*)(w1 + c * 32);
        const float4* w2p = (const float4*)(w2 + ((c & 7) * 32 + (c >> 3)) * 32);
#pragma unroll
        for (int i = 0; i < 8; ++i) { w1r[i] = w1p[i]; w2r[i] = w2p[i]; }
    }
    const float bb = bias[c];
    const int l2 = c & 7;
    const int kb = c >> 5;

    // blend-phase role: (row-in-iter, lane)
    const int rr   = __builtin_amdgcn_readfirstlane(threadIdx.x >> 6); // wave-uniform
    const int lane = threadIdx.x & 63;

    const int row_base = blockIdx.x * ROWS_PER_BLK;   // 16 | 8192 -> never straddles b
    const int b = row_base >> 13;
    const float4* x4 = (const float4*)(x + (size_t)b * NPTS * CH);

    for (int it = 0; it < ROWS_PER_BLK / ROWS_PER_IT; ++it) {
        const int row  = row_base + it * ROWS_PER_IT + rr;   // global row (wave-uniform)
        const int rloc = row & (NPTS - 1);                   // row within batch b

        // ---- softmax weights (wave-uniform scalar loads) ----
        float d[KNB];
        int   nb[KNB];
#pragma unroll
        for (int k = 0; k < KNB; ++k) {
            d[k]  = dist[(size_t)row * KNB + k];
            nb[k] = idx[(size_t)row * KNB + k];
        }
        float mn = d[0];
#pragma unroll
        for (int k = 1; k < KNB; ++k) mn = fminf(mn, d[k]);
        float e[KNB]; float sum = 0.f;
#pragma unroll
        for (int k = 0; k < KNB; ++k) { e[k] = __expf(mn - d[k]); sum += e[k]; }
        const float inv = 0.05f / sum;

        // ---- gather-blend, float4 per lane (1 KiB per wave instruction) ----
        float4 acc = x4[(size_t)rloc * 64 + lane];
        acc.x *= 0.95f; acc.y *= 0.95f; acc.z *= 0.95f; acc.w *= 0.95f;
#pragma unroll
        for (int k = 0; k < KNB; ++k) {
            const float4 g = x4[(size_t)nb[k] * 64 + lane];
            const float w = e[k] * inv;
            acc.x += w * g.x; acc.y += w * g.y; acc.z += w * g.z; acc.w += w * g.w;
        }
        ((float4*)&s1[rr][0])[lane] = acc;   // conflict-free linear b128 write
        __syncthreads();

        // ---- monarch stage A: f[c] = sum_p w1[k,q,p] * s1[k*32+p], 4 rows ----
#pragma unroll
        for (int r2 = 0; r2 < ROWS_PER_IT; ++r2) {
            const float4* sb = (const float4*)(&s1[r2][kb * 32]); // 2 distinct addrs/wave: broadcast
            float a = 0.f;
#pragma unroll
            for (int p4 = 0; p4 < 8; ++p4) {
                const float4 s = sb[p4];
                a += w1r[p4].x * s.x + w1r[p4].y * s.y
                   + w1r[p4].z * s.z + w1r[p4].w * s.w;
            }
            fmid[r2][c] = a;                 // bank = c%32: conflict-free
        }
        __syncthreads();

        // ---- monarch stage B: t[s*8+l2] = bias + sum_r w2[l2,s,r]*f[r*8+l2] ----
#pragma unroll
        for (int r2 = 0; r2 < ROWS_PER_IT; ++r2) {
            float a = bb;
#pragma unroll
            for (int r4 = 0; r4 < 8; ++r4) {
                a += w2r[r4].x * fmid[r2][(4 * r4 + 0) * 8 + l2];
                a += w2r[r4].y * fmid[r2][(4 * r4 + 1) * 8 + l2];
                a += w2r[r4].z * fmid[r2][(4 * r4 + 2) * 8 + l2];
                a += w2r[r4].w * fmid[r2][(4 * r4 + 3) * 8 + l2];
            }
            t[(size_t)(row_base + it * ROWS_PER_IT + r2) * CH + c] = a; // coalesced 1 KiB
        }
        // no barrier here: next iteration's s1 writes are fenced by the barrier
        // after the blend, and fmid rewrites by the barrier after stage A.
        __syncthreads();
    }
}

// ---------------------------------------------------------------------------
// Stage 2 (unchanged): out[row] = 0.95*t[row] + 0.05*sum_k w_k*t[b,idx_k] + rf
// ---------------------------------------------------------------------------
__global__ __launch_bounds__(256) void pm_stage2(
    const float* __restrict__ t, const float* __restrict__ dist,
    const int* __restrict__ idx, const float* __restrict__ rf,
    float* __restrict__ out)
{
    const int row  = blockIdx.x * 4 + (threadIdx.x >> 6);
    const int lane = threadIdx.x & 63;
    const int b    = row >> 13;

    float d[KNB];
#pragma unroll
    for (int k = 0; k < KNB; ++k) d[k] = dist[(size_t)row * KNB + k];
    float mn = d[0];
#pragma unroll
    for (int k = 1; k < KNB; ++k) mn = fminf(mn, d[k]);
    float e[KNB]; float sum = 0.f;
#pragma unroll
    for (int k = 0; k < KNB; ++k) { e[k] = __expf(mn - d[k]); sum += e[k]; }
    const float inv = 0.05f / sum;

    const float4* t4 = (const float4*)t;
    float4 acc = t4[(size_t)row * 64 + lane];
    acc.x *= 0.95f; acc.y *= 0.95f; acc.z *= 0.95f; acc.w *= 0.95f;

    const size_t bbase = (size_t)b * NPTS * 64;
#pragma unroll
    for (int k = 0; k < KNB; ++k) {
        const int nb = idx[(size_t)row * KNB + k];
        const float4 g = t4[bbase + (size_t)nb * 64 + lane];
        const float w = e[k] * inv;
        acc.x += w * g.x; acc.y += w * g.y; acc.z += w * g.z; acc.w += w * g.w;
    }

    const float4 r = ((const float4*)rf)[(size_t)row * 64 + lane];
    acc.x += r.x; acc.y += r.y; acc.z += r.z; acc.w += r.w;
    ((float4*)out)[(size_t)row * 64 + lane] = acc;
}

extern "C" void kernel_launch(void* const* d_in, const int* in_sizes, int n_in,
                              void* d_out, int out_size, void* d_ws, size_t ws_size,
                              hipStream_t stream) {
    const float* x    = (const float*)d_in[0];
    const float* dist = (const float*)d_in[1];
    const int*   idx  = (const int*)d_in[2];
    const float* rf   = (const float*)d_in[3];
    const float* w1   = (const float*)d_in[4];
    const float* w2   = (const float*)d_in[5];
    const float* bias = (const float*)d_in[6];
    float* out = (float*)d_out;
    float* t   = (float*)d_ws;   // 64 MiB intermediate (B,N,C) fp32

    pm_stage1<<<NROWS / ROWS_PER_BLK, 256, 0, stream>>>(x, dist, idx, w1, w2, bias, t);
    pm_stage2<<<NROWS / 4, 256, 0, stream>>>(t, dist, idx, rf, out);
}

// Round 3
// 281.103 us; speedup vs baseline: 2.4310x; 1.0933x over previous
//
#include <hip/hip_runtime.h>

// Problem constants (B=8, N=8192, C=256, K=8, nblocks=8, blk=32)
#define NPTS 8192
#define CH   256
#define KNB  8
#define NROWS 65536        // B*N
#define ROWS_PER_BLK 16    // rows each stage1 block processes
#define ROWS_PER_IT  4     // rows per barrier-delimited iteration

typedef unsigned short ushort_t;

// float -> bf16 with round-to-nearest-even
__device__ __forceinline__ ushort_t f32_to_bf16(float f) {
    unsigned int b = __float_as_uint(f);
    b += 0x7FFFu + ((b >> 16) & 1u);
    return (ushort_t)(b >> 16);
}
__device__ __forceinline__ float bf16_to_f32(ushort_t u) {
    return __uint_as_float(((unsigned int)u) << 16);
}

// ---------------------------------------------------------------------------
// Stage 1: s1 = rectify(x); t = monarch(s1), stored as bf16.
// Block = 256 threads, 16 rows in 4 iterations; weights hoisted to registers.
// ---------------------------------------------------------------------------
__global__ __launch_bounds__(256) void pm_stage1(
    const float* __restrict__ x, const float* __restrict__ dist,
    const int* __restrict__ idx, const float* __restrict__ w1,
    const float* __restrict__ w2, const float* __restrict__ bias,
    ushort_t* __restrict__ t)
{
    const int c = threadIdx.x;

    __shared__ float s1[ROWS_PER_IT][CH];
    __shared__ float fmid[ROWS_PER_IT][CH];

    // hoisted weights: stage A row w1[c*32..], stage B row w2[(l2*32+s)*32..]
    float4 w1r[8], w2r[8];
    {
        const float4* w1p = (const float4*)(w1 + c * 32);
        const float4* w2p = (const float4*)(w2 + ((c & 7) * 32 + (c >> 3)) * 32);
#pragma unroll
        for (int i = 0; i < 8; ++i) { w1r[i] = w1p[i]; w2r[i] = w2p[i]; }
    }
    const float bb = bias[c];
    const int l2 = c & 7;
    const int kb = c >> 5;

    const int rr   = __builtin_amdgcn_readfirstlane(threadIdx.x >> 6);
    const int lane = threadIdx.x & 63;

    const int row_base = blockIdx.x * ROWS_PER_BLK;   // 16 | 8192: same b all rows
    const int b = row_base >> 13;
    const float4* x4 = (const float4*)(x + (size_t)b * NPTS * CH);

    for (int it = 0; it < ROWS_PER_BLK / ROWS_PER_IT; ++it) {
        const int row  = row_base + it * ROWS_PER_IT + rr;   // wave-uniform
        const int rloc = row & (NPTS - 1);

        float d[KNB]; int nb[KNB];
#pragma unroll
        for (int k = 0; k < KNB; ++k) {
            d[k]  = dist[(size_t)row * KNB + k];
            nb[k] = idx[(size_t)row * KNB + k];
        }
        float mn = d[0];
#pragma unroll
        for (int k = 1; k < KNB; ++k) mn = fminf(mn, d[k]);
        float e[KNB]; float sum = 0.f;
#pragma unroll
        for (int k = 0; k < KNB; ++k) { e[k] = __expf(mn - d[k]); sum += e[k]; }
        const float inv = 0.05f / sum;

        // gather-blend, float4 per lane (1 KiB per wave instruction)
        float4 acc = x4[(size_t)rloc * 64 + lane];
        acc.x *= 0.95f; acc.y *= 0.95f; acc.z *= 0.95f; acc.w *= 0.95f;
#pragma unroll
        for (int k = 0; k < KNB; ++k) {
            const float4 g = x4[(size_t)nb[k] * 64 + lane];
            const float w = e[k] * inv;
            acc.x += w * g.x; acc.y += w * g.y; acc.z += w * g.z; acc.w += w * g.w;
        }
        ((float4*)&s1[rr][0])[lane] = acc;
        __syncthreads();

        // monarch stage A
#pragma unroll
        for (int r2 = 0; r2 < ROWS_PER_IT; ++r2) {
            const float4* sb = (const float4*)(&s1[r2][kb * 32]);
            float a = 0.f;
#pragma unroll
            for (int p4 = 0; p4 < 8; ++p4) {
                const float4 s = sb[p4];
                a += w1r[p4].x * s.x + w1r[p4].y * s.y
                   + w1r[p4].z * s.z + w1r[p4].w * s.w;
            }
            fmid[r2][c] = a;
        }
        __syncthreads();

        // monarch stage B -> bf16 store
#pragma unroll
        for (int r2 = 0; r2 < ROWS_PER_IT; ++r2) {
            float a = bb;
#pragma unroll
            for (int r4 = 0; r4 < 8; ++r4) {
                a += w2r[r4].x * fmid[r2][(4 * r4 + 0) * 8 + l2];
                a += w2r[r4].y * fmid[r2][(4 * r4 + 1) * 8 + l2];
                a += w2r[r4].z * fmid[r2][(4 * r4 + 2) * 8 + l2];
                a += w2r[r4].w * fmid[r2][(4 * r4 + 3) * 8 + l2];
            }
            t[(size_t)(row_base + it * ROWS_PER_IT + r2) * CH + c] = f32_to_bf16(a);
        }
        __syncthreads();
    }
}

// ---------------------------------------------------------------------------
// Stage 2: out = 0.95*t + 0.05*sum_k w_k*t[b,idx_k] + rf  (t in bf16)
// One wave per row, 4 rows per wave (unrolled), lane owns 4 channels.
// ---------------------------------------------------------------------------
__global__ __launch_bounds__(256) void pm_stage2(
    const ushort_t* __restrict__ t, const float* __restrict__ dist,
    const int* __restrict__ idx, const float* __restrict__ rf,
    float* __restrict__ out)
{
    const int w    = __builtin_amdgcn_readfirstlane(threadIdx.x >> 6);
    const int lane = threadIdx.x & 63;
    const int wrow0 = blockIdx.x * 16 + w * 4;     // 4 consecutive rows per wave
    const int b     = wrow0 >> 13;                 // 16-aligned: same b for all 4
    const ushort4* tb = (const ushort4*)(t + (size_t)b * NPTS * CH);

#pragma unroll
    for (int r = 0; r < 4; ++r) {
        const int row  = wrow0 + r;                // wave-uniform
        const int rloc = row & (NPTS - 1);

        float d[KNB]; int nb[KNB];
#pragma unroll
        for (int k = 0; k < KNB; ++k) {
            d[k]  = dist[(size_t)row * KNB + k];
            nb[k] = idx[(size_t)row * KNB + k];
        }
        float mn = d[0];
#pragma unroll
        for (int k = 1; k < KNB; ++k) mn = fminf(mn, d[k]);
        float e[KNB]; float sum = 0.f;
#pragma unroll
        for (int k = 0; k < KNB; ++k) { e[k] = __expf(mn - d[k]); sum += e[k]; }
        const float inv = 0.05f / sum;

        // center row (coalesced 512 B) + 8 gathers (each 512 B, coalesced)
        const ushort4 c0 = tb[(size_t)rloc * 64 + lane];
        ushort4 g[KNB];
#pragma unroll
        for (int k = 0; k < KNB; ++k) g[k] = tb[(size_t)nb[k] * 64 + lane];

        float4 acc;
        acc.x = 0.95f * bf16_to_f32(c0.x);
        acc.y = 0.95f * bf16_to_f32(c0.y);
        acc.z = 0.95f * bf16_to_f32(c0.z);
        acc.w = 0.95f * bf16_to_f32(c0.w);
#pragma unroll
        for (int k = 0; k < KNB; ++k) {
            const float wk = e[k] * inv;
            acc.x += wk * bf16_to_f32(g[k].x);
            acc.y += wk * bf16_to_f32(g[k].y);
            acc.z += wk * bf16_to_f32(g[k].z);
            acc.w += wk * bf16_to_f32(g[k].w);
        }

        const float4 rv = ((const float4*)rf)[(size_t)row * 64 + lane];
        acc.x += rv.x; acc.y += rv.y; acc.z += rv.z; acc.w += rv.w;
        ((float4*)out)[(size_t)row * 64 + lane] = acc;
    }
}

extern "C" void kernel_launch(void* const* d_in, const int* in_sizes, int n_in,
                              void* d_out, int out_size, void* d_ws, size_t ws_size,
                              hipStream_t stream) {
    const float* x    = (const float*)d_in[0];
    const float* dist = (const float*)d_in[1];
    const int*   idx  = (const int*)d_in[2];
    const float* rf   = (const float*)d_in[3];
    const float* w1   = (const float*)d_in[4];
    const float* w2   = (const float*)d_in[5];
    const float* bias = (const float*)d_in[6];
    float* out = (float*)d_out;
    ushort_t* t = (ushort_t*)d_ws;   // 32 MiB bf16 intermediate (B,N,C)

    pm_stage1<<<NROWS / ROWS_PER_BLK, 256, 0, stream>>>(x, dist, idx, w1, w2, bias, t);
    pm_stage2<<<NROWS / 16, 256, 0, stream>>>(t, dist, idx, rf, out);
}

// Round 4
// 279.313 us; speedup vs baseline: 2.4466x; 1.0064x over previous
//
#include <hip/hip_runtime.h>

// Problem constants (B=8, N=8192, C=256, K=8, nblocks=8, blk=32)
#define NPTS 8192
#define CH   256
#define KNB  8
#define NROWS 65536        // B*N
#define ROWS_PER_BLK 16
#define ROWS_PER_IT  4
#define FT_STRIDE 36       // fT row stride: 16B-aligned, <=2-way bank alias (free)

typedef unsigned short ushort_t;

__device__ __forceinline__ ushort_t f32_to_bf16(float f) {
    unsigned int b = __float_as_uint(f);
    b += 0x7FFFu + ((b >> 16) & 1u);
    return (ushort_t)(b >> 16);
}
__device__ __forceinline__ float bf16_to_f32(ushort_t u) {
    return __uint_as_float(((unsigned int)u) << 16);
}
__device__ __forceinline__ unsigned int pack_bf16(float lo, float hi) {
    return (unsigned int)f32_to_bf16(lo) | ((unsigned int)f32_to_bf16(hi) << 16);
}

// ---------------------------------------------------------------------------
// Prepass: x fp32 -> bf16 (halves gather bytes; 4 MB/batch-slice = L2-resident)
// Each thread converts 8 floats: 2 float4 loads -> 1 uint4 (ushort8) store.
// ---------------------------------------------------------------------------
__global__ __launch_bounds__(256) void pm_conv(
    const float4* __restrict__ x, uint4* __restrict__ xb)
{
    const size_t i = (size_t)blockIdx.x * 256 + threadIdx.x;
    const float4 a = x[2 * i];
    const float4 c = x[2 * i + 1];
    uint4 o;
    o.x = pack_bf16(a.x, a.y);
    o.y = pack_bf16(a.z, a.w);
    o.z = pack_bf16(c.x, c.y);
    o.w = pack_bf16(c.z, c.w);
    xb[i] = o;
}

// ---------------------------------------------------------------------------
// Stage 1: s1 = rectify(x_bf16); t = monarch(s1) -> bf16.
// fT layout (transposed, stride-36) turns stage B's 32 ds_read_b32/thread
// into 8 ds_read_b128/thread (conflict-free).
// ---------------------------------------------------------------------------
__global__ __launch_bounds__(256) void pm_stage1(
    const ushort_t* __restrict__ xb, const float* __restrict__ dist,
    const int* __restrict__ idx, const float* __restrict__ w1,
    const float* __restrict__ w2, const float* __restrict__ bias,
    ushort_t* __restrict__ t)
{
    const int c = threadIdx.x;

    __shared__ float s1[ROWS_PER_IT][CH];
    __shared__ float fT[ROWS_PER_IT][8 * FT_STRIDE];

    // hoisted weights
    float4 w1r[8], w2r[8];
    {
        const float4* w1p = (const float4*)(w1 + c * 32);
        const float4* w2p = (const float4*)(w2 + ((c & 7) * 32 + (c >> 3)) * 32);
#pragma unroll
        for (int i = 0; i < 8; ++i) { w1r[i] = w1p[i]; w2r[i] = w2p[i]; }
    }
    const float bb = bias[c];
    const int l2   = c & 7;
    const int kb   = c >> 5;
    const int ftw  = l2 * FT_STRIDE + (c >> 3);   // stage A output slot (f linear idx = c)

    const int rr   = __builtin_amdgcn_readfirstlane(threadIdx.x >> 6);
    const int lane = threadIdx.x & 63;

    const int row_base = blockIdx.x * ROWS_PER_BLK;
    const int b = row_base >> 13;
    const ushort4* x4 = (const ushort4*)(xb + (size_t)b * NPTS * CH);

    for (int it = 0; it < ROWS_PER_BLK / ROWS_PER_IT; ++it) {
        const int row  = row_base + it * ROWS_PER_IT + rr;   // wave-uniform
        const int rloc = row & (NPTS - 1);

        float d[KNB]; int nb[KNB];
#pragma unroll
        for (int k = 0; k < KNB; ++k) {
            d[k]  = dist[(size_t)row * KNB + k];
            nb[k] = idx[(size_t)row * KNB + k];
        }

        // issue all gathers (8B/lane = 512B/wave each) before consuming
        const ushort4 c0 = x4[(size_t)rloc * 64 + lane];
        ushort4 g[KNB];
#pragma unroll
        for (int k = 0; k < KNB; ++k) g[k] = x4[(size_t)nb[k] * 64 + lane];

        float mn = d[0];
#pragma unroll
        for (int k = 1; k < KNB; ++k) mn = fminf(mn, d[k]);
        float e[KNB]; float sum = 0.f;
#pragma unroll
        for (int k = 0; k < KNB; ++k) { e[k] = __expf(mn - d[k]); sum += e[k]; }
        const float inv = 0.05f / sum;

        float4 acc;
        acc.x = 0.95f * bf16_to_f32(c0.x);
        acc.y = 0.95f * bf16_to_f32(c0.y);
        acc.z = 0.95f * bf16_to_f32(c0.z);
        acc.w = 0.95f * bf16_to_f32(c0.w);
#pragma unroll
        for (int k = 0; k < KNB; ++k) {
            const float w = e[k] * inv;
            acc.x += w * bf16_to_f32(g[k].x);
            acc.y += w * bf16_to_f32(g[k].y);
            acc.z += w * bf16_to_f32(g[k].z);
            acc.w += w * bf16_to_f32(g[k].w);
        }
        ((float4*)&s1[rr][0])[lane] = acc;
        __syncthreads();

        // stage A: f[c] = sum_p w1[kb,q,p]*s1[kb*32+p]; write to fT transposed
#pragma unroll
        for (int r2 = 0; r2 < ROWS_PER_IT; ++r2) {
            const float4* sb = (const float4*)(&s1[r2][kb * 32]); // 2 addrs/wave: free
            float a = 0.f;
#pragma unroll
            for (int p4 = 0; p4 < 8; ++p4) {
                const float4 s = sb[p4];
                a += w1r[p4].x * s.x + w1r[p4].y * s.y
                   + w1r[p4].z * s.z + w1r[p4].w * s.w;
            }
            fT[r2][ftw] = a;    // <=2-way bank alias: free
        }
        __syncthreads();

        // stage B: t[c] = bias + sum_r w2[l2,s,r]*f[r*8+l2], f via fT b128 reads
#pragma unroll
        for (int r2 = 0; r2 < ROWS_PER_IT; ++r2) {
            const float4* fp = (const float4*)(&fT[r2][l2 * FT_STRIDE]); // 8 addrs, 8 bank-groups: free
            float a = bb;
#pragma unroll
            for (int r4 = 0; r4 < 8; ++r4) {
                const float4 f = fp[r4];
                a += w2r[r4].x * f.x + w2r[r4].y * f.y
                   + w2r[r4].z * f.z + w2r[r4].w * f.w;
            }
            t[(size_t)(row_base + it * ROWS_PER_IT + r2) * CH + c] = f32_to_bf16(a);
        }
        // no barrier: s1 rewrite is fenced by the post-stage-A barrier; fT
        // rewrite happens after the next post-blend barrier.
        __syncthreads();   // replaces barrier-1 of next iteration (post-blend)
        // NOTE: the barrier above is the post-blend barrier of the NEXT
        // iteration only in spirit; keep structure simple & correct: blend of
        // next iteration happens after this barrier, stage-B fT reads are done.
    }
}

// ---------------------------------------------------------------------------
// Stage 2: out = 0.95*t + 0.05*sum_k w_k*t[b,idx_k] + rf  (t bf16)
// One wave per 4 rows; ALL 36 gathers + 4 rf loads issued before consumption.
// ---------------------------------------------------------------------------
__global__ __launch_bounds__(256) void pm_stage2(
    const ushort_t* __restrict__ t, const float* __restrict__ dist,
    const int* __restrict__ idx, const float* __restrict__ rf,
    float* __restrict__ out)
{
    const int w     = __builtin_amdgcn_readfirstlane(threadIdx.x >> 6);
    const int lane  = threadIdx.x & 63;
    const int wrow0 = blockIdx.x * 16 + w * 4;
    const int b     = wrow0 >> 13;
    const ushort4* tb = (const ushort4*)(t + (size_t)b * NPTS * CH);

    int   nb[4][KNB];
    float d [4][KNB];
#pragma unroll
    for (int r = 0; r < 4; ++r)
#pragma unroll
        for (int k = 0; k < KNB; ++k) {
            nb[r][k] = idx[(size_t)(wrow0 + r) * KNB + k];
            d [r][k] = dist[(size_t)(wrow0 + r) * KNB + k];
        }

    // issue everything
    ushort4 c0[4], g[4][KNB];
    float4  rv[4];
#pragma unroll
    for (int r = 0; r < 4; ++r) {
        const int rloc = (wrow0 + r) & (NPTS - 1);
        c0[r] = tb[(size_t)rloc * 64 + lane];
        rv[r] = ((const float4*)rf)[(size_t)(wrow0 + r) * 64 + lane];
#pragma unroll
        for (int k = 0; k < KNB; ++k) g[r][k] = tb[(size_t)nb[r][k] * 64 + lane];
    }

#pragma unroll
    for (int r = 0; r < 4; ++r) {
        float mn = d[r][0];
#pragma unroll
        for (int k = 1; k < KNB; ++k) mn = fminf(mn, d[r][k]);
        float e[KNB]; float sum = 0.f;
#pragma unroll
        for (int k = 0; k < KNB; ++k) { e[k] = __expf(mn - d[r][k]); sum += e[k]; }
        const float inv = 0.05f / sum;

        float4 acc;
        acc.x = 0.95f * bf16_to_f32(c0[r].x) + rv[r].x;
        acc.y = 0.95f * bf16_to_f32(c0[r].y) + rv[r].y;
        acc.z = 0.95f * bf16_to_f32(c0[r].z) + rv[r].z;
        acc.w = 0.95f * bf16_to_f32(c0[r].w) + rv[r].w;
#pragma unroll
        for (int k = 0; k < KNB; ++k) {
            const float wk = e[k] * inv;
            acc.x += wk * bf16_to_f32(g[r][k].x);
            acc.y += wk * bf16_to_f32(g[r][k].y);
            acc.z += wk * bf16_to_f32(g[r][k].z);
            acc.w += wk * bf16_to_f32(g[r][k].w);
        }
        ((float4*)out)[(size_t)(wrow0 + r) * 64 + lane] = acc;
    }
}

extern "C" void kernel_launch(void* const* d_in, const int* in_sizes, int n_in,
                              void* d_out, int out_size, void* d_ws, size_t ws_size,
                              hipStream_t stream) {
    const float* x    = (const float*)d_in[0];
    const float* dist = (const float*)d_in[1];
    const int*   idx  = (const int*)d_in[2];
    const float* rf   = (const float*)d_in[3];
    const float* w1   = (const float*)d_in[4];
    const float* w2   = (const float*)d_in[5];
    const float* bias = (const float*)d_in[6];
    float* out = (float*)d_out;

    ushort_t* t  = (ushort_t*)d_ws;                            // 32 MiB bf16 t
    ushort_t* xb = (ushort_t*)((char*)d_ws + (size_t)NROWS * CH * 2); // 32 MiB bf16 x

    pm_conv  <<<NROWS * CH / (256 * 8), 256, 0, stream>>>((const float4*)x, (uint4*)xb);
    pm_stage1<<<NROWS / ROWS_PER_BLK, 256, 0, stream>>>(xb, dist, idx, w1, w2, bias, t);
    pm_stage2<<<NROWS / 16, 256, 0, stream>>>(t, dist, idx, rf, out);
}